// Round 9
// baseline (481.962 us; speedup 1.0000x reference)
//
#include <hip/hip_runtime.h>
#include <hip/hip_bf16.h>

#define NS 7
#define NA 131072
#define AEVD 1008
#define KP1 1024
#define N1 256
#define N2 192
#define N3 160
#define H2P 200
#define H3P 168

typedef __attribute__((ext_vector_type(8))) short short8;
typedef __attribute__((ext_vector_type(8))) unsigned short ushortx8;
typedef __attribute__((ext_vector_type(4))) float f32x4;
typedef __attribute__((ext_vector_type(4))) float fvec4;
typedef unsigned short u16;
typedef unsigned int u32;

// LDS-only barrier (register vmem prefetches stay in flight across it)
#define BAR() asm volatile("s_waitcnt lgkmcnt(0)\ns_barrier" ::: "memory")

__device__ __forceinline__ u16 f2bf(float f) {
  unsigned u = __builtin_bit_cast(unsigned, f);
  u += 0x7fffu + ((u >> 16) & 1u);
  return (u16)(u >> 16);
}
__device__ __forceinline__ u16 f2bf_hw(float f) {
  __hip_bfloat16 h = __float2bfloat16(f);
  return __builtin_bit_cast(u16, h);
}
__device__ __forceinline__ float bf2f(u16 h) {
  return __builtin_bit_cast(float, ((unsigned)h) << 16);
}
__device__ __forceinline__ float celu_f(float x) {
  return x > 0.f ? x : 0.1f * (__expf(x * 10.f) - 1.f);
}
__device__ __forceinline__ void gload_lds16(const void* src, void* lds) {
  __builtin_amdgcn_global_load_lds(
      (const __attribute__((address_space(1))) u32*)src,
      (__attribute__((address_space(3))) u32*)lds, 16, 0, 0);
}

// ---------------- bucketing ----------------
__global__ void count_kernel(const int* __restrict__ species, int* __restrict__ counts) {
  __shared__ int h[NS];
  if (threadIdx.x < NS) h[threadIdx.x] = 0;
  __syncthreads();
  int i = blockIdx.x * blockDim.x + threadIdx.x;
  if (i < NA) atomicAdd(&h[species[i]], 1);
  __syncthreads();
  if (threadIdx.x < NS) atomicAdd(&counts[threadIdx.x], h[threadIdx.x]);
}

__global__ void scan_kernel(const int* __restrict__ counts, int* __restrict__ offsets,
                            int* __restrict__ cursors, int* __restrict__ gstart1,
                            int* __restrict__ gstart2) {
  int off = 0, g1 = 0, g2 = 0;
  for (int e = 0; e < NS; ++e) {
    offsets[e] = off; cursors[e] = off; gstart1[e] = g1; gstart2[e] = g2;
    off += counts[e];
    g1 += (counts[e] + 127) >> 7;
    g2 += (counts[e] + 63) >> 6;
  }
  offsets[NS] = off; gstart1[NS] = g1; gstart2[NS] = g2;
}

__global__ void scatter_kernel(const int* __restrict__ species, int* __restrict__ cursors,
                               int* __restrict__ idx) {
  __shared__ int h[NS], lb[NS];
  if (threadIdx.x < NS) h[threadIdx.x] = 0;
  __syncthreads();
  int i = blockIdx.x * blockDim.x + threadIdx.x;
  int s = species[i];
  int lpos = atomicAdd(&h[s], 1);
  __syncthreads();
  if (threadIdx.x < NS) lb[threadIdx.x] = atomicAdd(&cursors[threadIdx.x], h[threadIdx.x]);
  __syncthreads();
  idx[lb[s] + lpos] = i;
}

// ---------------- weight convert: dst[e][n][kp] = bf16(src[e][k][n]), zero pad ----------------
__global__ void convert_w(const float* __restrict__ src, u16* __restrict__ dst,
                          int K, int N, int KP) {
  long total = (long)NS * N * KP;
  for (long i = (long)blockIdx.x * blockDim.x + threadIdx.x; i < total;
       i += (long)gridDim.x * blockDim.x) {
    int kp = (int)(i % KP);
    long t2 = i / KP;
    int n = (int)(t2 % N);
    int e = (int)(t2 / N);
    float v = (kp < K) ? src[((long)e * K + kp) * N + n] : 0.f;
    dst[i] = f2bf(v);
  }
}

// ---------------- K1: layer-1 grouped GEMM, 128x256 tile, 8 waves ----------------
__global__ __launch_bounds__(512, 4) void gemm1(
    const int* __restrict__ idx, const int* __restrict__ counts,
    const int* __restrict__ offsets, const int* __restrict__ gstart,
    const float* __restrict__ aev, const u16* __restrict__ W1t,
    const float* __restrict__ b1, u16* __restrict__ h1g) {
  __shared__ __align__(16) float A[2][128 * 32];   // 2 x 16 KB, linear for gl_lds

  // bijective XCD chunk swizzle (m204)
  int gd = gridDim.x, b0 = blockIdx.x;
  int q = gd >> 3, r = gd & 7;
  int xcd = b0 & 7, ii = b0 >> 3;
  int bid = (xcd < r ? xcd * (q + 1) : r * (q + 1) + (xcd - r) * q) + ii;
  if (bid >= gstart[NS]) return;
  int e = 0;
#pragma unroll
  for (int s = 1; s < NS; ++s)
    if (bid >= gstart[s]) e = s;
  int t0 = bid - gstart[e];
  int base = offsets[e] + (t0 << 7);
  int mcount = counts[e] - (t0 << 7);
  if (mcount > 128) mcount = 128;

  int tid = threadIdx.x, lane = tid & 63, w = tid >> 6;
  int lr = lane & 15, kg = lane >> 4;
  int wr = w & 1, wc = w >> 1;

  // A staging: wave w covers rows w*16..w*16+15, two gl_lds calls (8 rows each)
  int srow0 = w * 16 + (lane >> 3);
  int srow1 = srow0 + 8;
  int rr0 = srow0 < mcount ? srow0 : mcount - 1;
  int rr1 = srow1 < mcount ? srow1 : mcount - 1;
  const float* sp0 = aev + (size_t)idx[base + rr0] * AEVD;
  const float* sp1 = aev + (size_t)idx[base + rr1] * AEVD;
  // XOR source pre-swizzle (rule #21): phys slot (lane&7) holds logical slot ^(row&7)
  int so0 = ((lane & 7) ^ (srow0 & 7)) << 4;   // bytes within 128B row-chunk
  int so1 = ((lane & 7) ^ (srow1 & 7)) << 4;
  int so0t = so0 >= 64 ? so0 - 64 : so0;       // k>=1008 tail: any valid floats x W=0
  int so1t = so1 >= 64 ? so1 - 64 : so1;

  auto stageA = [&](int c, int buf) {
    int o0 = (c == 31) ? so0t : so0;
    int o1 = (c == 31) ? so1t : so1;
    gload_lds16((const char*)sp0 + (size_t)c * 128 + o0, (char*)&A[buf][0] + w * 2048);
    gload_lds16((const char*)sp1 + (size_t)c * 128 + o1, (char*)&A[buf][0] + w * 2048 + 1024);
  };

  const u16* Wb1 = W1t + ((size_t)e * N1 + (wc * 64 + lr)) * KP1 + kg * 8;
  auto loadB1 = [&](int c, short8 (&d)[4]) {
#pragma unroll
    for (int ni = 0; ni < 4; ++ni)
      d[ni] = *(const short8*)(Wb1 + (size_t)ni * 16 * KP1 + c * 32);
  };

  f32x4 acc[4][4] = {};
  auto step = [&](int c, int buf, short8 (&ring)[4]) {
    if (c + 1 < 32) stageA(c + 1, buf ^ 1);
    short8 af[4];
#pragma unroll
    for (int mi = 0; mi < 4; ++mi) {
      int R = wr * 64 + mi * 16 + lr;
      int p0 = (2 * kg) ^ (R & 7);
      int p1 = (2 * kg + 1) ^ (R & 7);
      fvec4 f0 = *(const fvec4*)&A[buf][R * 32 + p0 * 4];
      fvec4 f1 = *(const fvec4*)&A[buf][R * 32 + p1 * 4];
      ushortx8 pk;
      pk[0] = f2bf_hw(f0.x); pk[1] = f2bf_hw(f0.y); pk[2] = f2bf_hw(f0.z); pk[3] = f2bf_hw(f0.w);
      pk[4] = f2bf_hw(f1.x); pk[5] = f2bf_hw(f1.y); pk[6] = f2bf_hw(f1.z); pk[7] = f2bf_hw(f1.w);
      af[mi] = __builtin_bit_cast(short8, pk);
    }
    __builtin_amdgcn_s_setprio(1);
#pragma unroll
    for (int ni = 0; ni < 4; ++ni)
#pragma unroll
      for (int mi = 0; mi < 4; ++mi)
        acc[mi][ni] = __builtin_amdgcn_mfma_f32_16x16x32_bf16(af[mi], ring[ni], acc[mi][ni], 0, 0, 0);
    __builtin_amdgcn_s_setprio(0);
    if (c + 2 < 32) loadB1(c + 2, ring);
    __syncthreads();
  };

  stageA(0, 0);
  short8 rgA[4], rgB[4];
  loadB1(0, rgA); loadB1(1, rgB);
  __syncthreads();
  for (int c = 0; c < 32; c += 2) {
    step(c, 0, rgA);
    step(c + 1, 1, rgB);
  }

  // epilogue: bias + celu -> h1g (bucket-ordered, guarded)
#pragma unroll
  for (int ni = 0; ni < 4; ++ni) {
    int col = wc * 64 + ni * 16 + lr;
    float bias = b1[e * N1 + col];
#pragma unroll
    for (int mi = 0; mi < 4; ++mi)
#pragma unroll
      for (int rr = 0; rr < 4; ++rr) {
        int row = wr * 64 + mi * 16 + kg * 4 + rr;
        if (row < mcount)
          h1g[(size_t)(base + row) * N1 + col] = f2bf_hw(celu_f(acc[mi][ni][rr] + bias));
      }
  }
}

// ---------------- K2: layers 2/3 + head, 64 atoms/block, 4 waves ----------------
__global__ __launch_bounds__(256, 4) void mlp23(
    const int* __restrict__ idx, const int* __restrict__ counts,
    const int* __restrict__ offsets, const int* __restrict__ gstart,
    const u16* __restrict__ h1g,
    const u16* __restrict__ W2t, const float* __restrict__ b2,
    const u16* __restrict__ W3t, const float* __restrict__ b3,
    const u16* __restrict__ Wht, const float* __restrict__ bh,
    float* __restrict__ out) {
  __shared__ __align__(16) u16 H2[64 * H2P];
  __shared__ __align__(16) u16 H3[64 * H3P];

  int bid = blockIdx.x;
  if (bid >= gstart[NS]) return;
  int e = 0;
#pragma unroll
  for (int s = 1; s < NS; ++s)
    if (bid >= gstart[s]) e = s;
  int t0 = bid - gstart[e];
  int base = offsets[e] + (t0 << 6);
  int mcount = counts[e] - (t0 << 6);
  if (mcount > 64) mcount = 64;

  int tid = threadIdx.x, lane = tid & 63, w = tid >> 6;
  int lr = lane & 15, kg = lane >> 4;
  int mr2 = (w & 1) * 32;
  int nc2 = (w >> 1) * 96;

  // layer-2 A direct from h1g (L3-resident), depth-2 ring
  const u16* A0 = h1g + (size_t)(base + mr2 + lr) * N1 + kg * 8;
  const u16* A1 = A0 + (size_t)16 * N1;
  auto loadA2 = [&](int ks, short8& a0, short8& a1) {
    a0 = *(const short8*)(A0 + ks * 32);
    a1 = *(const short8*)(A1 + ks * 32);
  };
  const u16* Wb2 = W2t + ((size_t)e * N2 + (nc2 + lr)) * N1 + kg * 8;
  auto loadB2 = [&](int ks, short8 (&d)[6]) {
#pragma unroll
    for (int ni = 0; ni < 6; ++ni)
      d[ni] = *(const short8*)(Wb2 + (size_t)ni * 16 * N1 + ks * 32);
  };

  f32x4 acc2[2][6] = {};
  short8 aA0, aA1, aB0, aB1, r2a[6], r2b[6];
  loadA2(0, aA0, aA1); loadA2(1, aB0, aB1);
  loadB2(0, r2a); loadB2(1, r2b);
  auto mm2 = [&](short8& a0, short8& a1, short8 (&b)[6]) {
#pragma unroll
    for (int ni = 0; ni < 6; ++ni) {
      acc2[0][ni] = __builtin_amdgcn_mfma_f32_16x16x32_bf16(a0, b[ni], acc2[0][ni], 0, 0, 0);
      acc2[1][ni] = __builtin_amdgcn_mfma_f32_16x16x32_bf16(a1, b[ni], acc2[1][ni], 0, 0, 0);
    }
  };
  mm2(aA0, aA1, r2a); loadA2(2, aA0, aA1); loadB2(2, r2a);
  mm2(aB0, aB1, r2b); loadA2(3, aB0, aB1); loadB2(3, r2b);
  mm2(aA0, aA1, r2a); loadA2(4, aA0, aA1); loadB2(4, r2a);
  mm2(aB0, aB1, r2b); loadA2(5, aB0, aB1); loadB2(5, r2b);
  mm2(aA0, aA1, r2a); loadA2(6, aA0, aA1); loadB2(6, r2a);
  mm2(aB0, aB1, r2b); loadA2(7, aB0, aB1); loadB2(7, r2b);
  mm2(aA0, aA1, r2a);
  mm2(aB0, aB1, r2b);

  // layer-3 B ring prefetch (hoisted above epilogue-2 barrier)
  int mr3 = (w & 1) * 32;
  int nc3 = (w >> 1) * 80;
  const u16* Wb3 = W3t + ((size_t)e * N3 + (nc3 + lr)) * N2 + kg * 8;
  auto loadB3 = [&](int ks, short8 (&d)[5]) {
#pragma unroll
    for (int ni = 0; ni < 5; ++ni)
      d[ni] = *(const short8*)(Wb3 + (size_t)ni * 16 * N2 + ks * 32);
  };
  short8 r3a[5], r3b[5];
  loadB3(0, r3a); loadB3(1, r3b);

  // epilogue 2 -> H2
#pragma unroll
  for (int ni = 0; ni < 6; ++ni) {
    int col = nc2 + ni * 16 + lr;
    float bias = b2[e * N2 + col];
#pragma unroll
    for (int mi = 0; mi < 2; ++mi)
#pragma unroll
      for (int rr = 0; rr < 4; ++rr)
        H2[(mr2 + mi * 16 + kg * 4 + rr) * H2P + col] = f2bf_hw(celu_f(acc2[mi][ni][rr] + bias));
  }
  BAR();

  // layer 3: A from H2 (pitch 200 -> conflict-free), no barriers
  f32x4 acc3[2][5] = {};
  auto mm3 = [&](int ks, short8 (&b)[5]) {
    short8 a0 = *(const short8*)&H2[(mr3 + lr) * H2P + ks * 32 + kg * 8];
    short8 a1 = *(const short8*)&H2[(mr3 + 16 + lr) * H2P + ks * 32 + kg * 8];
#pragma unroll
    for (int ni = 0; ni < 5; ++ni) {
      acc3[0][ni] = __builtin_amdgcn_mfma_f32_16x16x32_bf16(a0, b[ni], acc3[0][ni], 0, 0, 0);
      acc3[1][ni] = __builtin_amdgcn_mfma_f32_16x16x32_bf16(a1, b[ni], acc3[1][ni], 0, 0, 0);
    }
  };
  mm3(0, r3a); loadB3(2, r3a);
  mm3(1, r3b); loadB3(3, r3b);
  mm3(2, r3a); loadB3(4, r3a);
  mm3(3, r3b); loadB3(5, r3b);
  mm3(4, r3a);
  mm3(5, r3b);

  // head weights prefetch (hoisted above epilogue-3 barrier)
  int hr_ = tid >> 2;
  int ho = (tid >> 1) & 1;
  int kh = tid & 1;
  const u16* wrp = Wht + ((size_t)e * 2 + ho) * N3 + kh * 80;
  ushortx8 wvv[10];
#pragma unroll
  for (int c = 0; c < 10; ++c) wvv[c] = *(const ushortx8*)&wrp[c * 8];

  // epilogue 3 -> H3
#pragma unroll
  for (int ni = 0; ni < 5; ++ni) {
    int col = nc3 + ni * 16 + lr;
    float bias = b3[e * N3 + col];
#pragma unroll
    for (int mi = 0; mi < 2; ++mi)
#pragma unroll
      for (int rr = 0; rr < 4; ++rr)
        H3[(mr3 + mi * 16 + kg * 4 + rr) * H3P + col] = f2bf_hw(celu_f(acc3[mi][ni][rr] + bias));
  }
  BAR();

  // head
  {
    float s = 0.f;
    const u16* hrow = &H3[hr_ * H3P + kh * 80];
#pragma unroll
    for (int c = 0; c < 10; ++c) {
      ushortx8 hv = *(const ushortx8*)&hrow[c * 8];
#pragma unroll
      for (int j = 0; j < 8; ++j) s += bf2f(hv[j]) * bf2f(wvv[c][j]);
    }
    s += __shfl_xor(s, 1);
    if (kh == 0 && hr_ < mcount) out[(size_t)idx[base + hr_] * 2 + ho] = s + bh[e * 2 + ho];
  }
}

extern "C" void kernel_launch(void* const* d_in, const int* in_sizes, int n_in,
                              void* d_out, int out_size, void* d_ws, size_t ws_size,
                              hipStream_t stream) {
  const int* species = (const int*)d_in[0];
  const float* aev = (const float*)d_in[1];
  const float* W1 = (const float*)d_in[2];
  const float* b1 = (const float*)d_in[3];
  const float* W2 = (const float*)d_in[4];
  const float* b2 = (const float*)d_in[5];
  const float* W3 = (const float*)d_in[6];
  const float* b3 = (const float*)d_in[7];
  const float* Wh = (const float*)d_in[8];
  const float* bh = (const float*)d_in[9];
  float* out = (float*)d_out;

  char* p = (char*)d_ws;
  u16* h1g = (u16*)p; p += (size_t)(NA + 256) * N1 * 2;   // 67.2 MB
  int* counts = (int*)p; p += 32;
  int* offsets = (int*)p; p += 64;
  int* cursors = (int*)p; p += 32;
  int* gstart1 = (int*)p; p += 64;
  int* gstart2 = (int*)p; p += 64;
  int* idx = (int*)p; p += (size_t)NA * 4;
  u16* W1t = (u16*)p; p += (size_t)NS * N1 * KP1 * 2;
  u16* W2t = (u16*)p; p += (size_t)NS * N2 * N1 * 2;
  u16* W3t = (u16*)p; p += (size_t)NS * N3 * N2 * 2;
  u16* Wht = (u16*)p; p += (size_t)NS * 2 * N3 * 2;

  (void)hipMemsetAsync(counts, 0, 32, stream);
  count_kernel<<<NA / 256, 256, 0, stream>>>(species, counts);
  scan_kernel<<<1, 1, 0, stream>>>(counts, offsets, cursors, gstart1, gstart2);
  scatter_kernel<<<NA / 256, 256, 0, stream>>>(species, cursors, idx);

  convert_w<<<2048, 256, 0, stream>>>(W1, W1t, AEVD, N1, KP1);
  convert_w<<<1024, 256, 0, stream>>>(W2, W2t, N1, N2, N1);
  convert_w<<<512, 256, 0, stream>>>(W3, W3t, N2, N3, N2);
  convert_w<<<16, 256, 0, stream>>>(Wh, Wht, N3, 2, N3);

  int grid1 = (NA >> 7) + NS;
  gemm1<<<grid1, 512, 0, stream>>>(idx, counts, offsets, gstart1, aev, W1t, b1, h1g);

  int grid2 = (NA >> 6) + NS;
  mlp23<<<grid2, 256, 0, stream>>>(idx, counts, offsets, gstart2, h1g,
                                   W2t, b2, W3t, b3, Wht, bh, out);
}

// Round 10
// 468.240 us; speedup vs baseline: 1.0293x; 1.0293x over previous
//
#include <hip/hip_runtime.h>
#include <hip/hip_bf16.h>

#define NS 7
#define NA 131072
#define AEVD 1008
#define KP1 1024
#define N1 256
#define N2 192
#define N3 160
#define H2P 200
#define H3P 168

typedef __attribute__((ext_vector_type(8))) short short8;
typedef __attribute__((ext_vector_type(8))) unsigned short ushortx8;
typedef __attribute__((ext_vector_type(4))) float f32x4;
typedef __attribute__((ext_vector_type(4))) float fvec4;
typedef unsigned short u16;
typedef unsigned int u32;

// LDS-only barrier (register vmem prefetches stay in flight across it)
#define BAR() asm volatile("s_waitcnt lgkmcnt(0)\ns_barrier" ::: "memory")

__device__ __forceinline__ u16 f2bf(float f) {
  unsigned u = __builtin_bit_cast(unsigned, f);
  u += 0x7fffu + ((u >> 16) & 1u);
  return (u16)(u >> 16);
}
__device__ __forceinline__ u16 f2bf_hw(float f) {
  __hip_bfloat16 h = __float2bfloat16(f);
  return __builtin_bit_cast(u16, h);
}
__device__ __forceinline__ float bf2f(u16 h) {
  return __builtin_bit_cast(float, ((unsigned)h) << 16);
}
__device__ __forceinline__ float celu_f(float x) {
  return x > 0.f ? x : 0.1f * (__expf(x * 10.f) - 1.f);
}
__device__ __forceinline__ void gload_lds16(const void* src, void* lds) {
  __builtin_amdgcn_global_load_lds(
      (const __attribute__((address_space(1))) u32*)src,
      (__attribute__((address_space(3))) u32*)lds, 16, 0, 0);
}

// ---------------- bucketing ----------------
__global__ void count_kernel(const int* __restrict__ species, int* __restrict__ counts) {
  __shared__ int h[NS];
  if (threadIdx.x < NS) h[threadIdx.x] = 0;
  __syncthreads();
  int i = blockIdx.x * blockDim.x + threadIdx.x;
  if (i < NA) atomicAdd(&h[species[i]], 1);
  __syncthreads();
  if (threadIdx.x < NS) atomicAdd(&counts[threadIdx.x], h[threadIdx.x]);
}

__global__ void scan_kernel(const int* __restrict__ counts, int* __restrict__ offsets,
                            int* __restrict__ cursors, int* __restrict__ gstart1,
                            int* __restrict__ gstart2) {
  int off = 0, g1 = 0, g2 = 0;
  for (int e = 0; e < NS; ++e) {
    offsets[e] = off; cursors[e] = off; gstart1[e] = g1; gstart2[e] = g2;
    off += counts[e];
    g1 += (counts[e] + 127) >> 7;
    g2 += (counts[e] + 63) >> 6;
  }
  offsets[NS] = off; gstart1[NS] = g1; gstart2[NS] = g2;
}

__global__ void scatter_kernel(const int* __restrict__ species, int* __restrict__ cursors,
                               int* __restrict__ idx) {
  __shared__ int h[NS], lb[NS];
  if (threadIdx.x < NS) h[threadIdx.x] = 0;
  __syncthreads();
  int i = blockIdx.x * blockDim.x + threadIdx.x;
  int s = species[i];
  int lpos = atomicAdd(&h[s], 1);
  __syncthreads();
  if (threadIdx.x < NS) lb[threadIdx.x] = atomicAdd(&cursors[threadIdx.x], h[threadIdx.x]);
  __syncthreads();
  idx[lb[s] + lpos] = i;
}

// ---------------- weight convert: dst[e][n][kp] = bf16(src[e][k][n]), zero pad ----------------
__global__ void convert_w(const float* __restrict__ src, u16* __restrict__ dst,
                          int K, int N, int KP) {
  long total = (long)NS * N * KP;
  for (long i = (long)blockIdx.x * blockDim.x + threadIdx.x; i < total;
       i += (long)gridDim.x * blockDim.x) {
    int kp = (int)(i % KP);
    long t2 = i / KP;
    int n = (int)(t2 % N);
    int e = (int)(t2 / N);
    float v = (kp < K) ? src[((long)e * K + kp) * N + n] : 0.f;
    dst[i] = f2bf(v);
  }
}

// ---------------- K1: layer-1 grouped GEMM, 128x256 tile, 8 waves ----------------
__global__ __launch_bounds__(512, 2) void gemm1(
    const int* __restrict__ idx, const int* __restrict__ counts,
    const int* __restrict__ offsets, const int* __restrict__ gstart,
    const float* __restrict__ aev, const u16* __restrict__ W1t,
    const float* __restrict__ b1, u16* __restrict__ h1g) {
  __shared__ __align__(16) float A[2][128 * 32];   // 2 x 16 KB, linear for gl_lds

  // bijective XCD chunk swizzle (m204)
  int gd = gridDim.x, b0 = blockIdx.x;
  int q = gd >> 3, r = gd & 7;
  int xcd = b0 & 7, ii = b0 >> 3;
  int bid = (xcd < r ? xcd * (q + 1) : r * (q + 1) + (xcd - r) * q) + ii;
  if (bid >= gstart[NS]) return;
  int e = 0;
#pragma unroll
  for (int s = 1; s < NS; ++s)
    if (bid >= gstart[s]) e = s;
  int t0 = bid - gstart[e];
  int base = offsets[e] + (t0 << 7);
  int mcount = counts[e] - (t0 << 7);
  if (mcount > 128) mcount = 128;

  int tid = threadIdx.x, lane = tid & 63, w = tid >> 6;
  int lr = lane & 15, kg = lane >> 4;
  int wr = w & 1, wc = w >> 1;

  // A staging: wave w covers rows w*16..w*16+15, two gl_lds calls (8 rows each)
  int srow0 = w * 16 + (lane >> 3);
  int srow1 = srow0 + 8;
  int rr0 = srow0 < mcount ? srow0 : mcount - 1;
  int rr1 = srow1 < mcount ? srow1 : mcount - 1;
  const float* sp0 = aev + (size_t)idx[base + rr0] * AEVD;
  const float* sp1 = aev + (size_t)idx[base + rr1] * AEVD;
  // XOR source pre-swizzle (rule #21): phys slot (lane&7) holds logical slot ^(row&7)
  int so0 = ((lane & 7) ^ (srow0 & 7)) << 4;   // bytes within 128B row-chunk
  int so1 = ((lane & 7) ^ (srow1 & 7)) << 4;
  int so0t = so0 >= 64 ? so0 - 64 : so0;       // k>=1008 tail: any finite floats x W=0
  int so1t = so1 >= 64 ? so1 - 64 : so1;

  auto stageA = [&](int c, int buf) {
    int o0 = (c == 31) ? so0t : so0;
    int o1 = (c == 31) ? so1t : so1;
    gload_lds16((const char*)sp0 + (size_t)c * 128 + o0, (char*)&A[buf][0] + w * 2048);
    gload_lds16((const char*)sp1 + (size_t)c * 128 + o1, (char*)&A[buf][0] + w * 2048 + 1024);
  };

  const u16* Wb1 = W1t + ((size_t)e * N1 + (wc * 64 + lr)) * KP1 + kg * 8;
  auto loadB1 = [&](int c, short8 (&d)[4]) {
#pragma unroll
    for (int ni = 0; ni < 4; ++ni)
      d[ni] = *(const short8*)(Wb1 + (size_t)ni * 16 * KP1 + c * 32);
  };

  f32x4 acc[4][4] = {};
  auto step = [&](int c, int buf, short8 (&ring)[4]) {
    if (c + 1 < 32) stageA(c + 1, buf ^ 1);
    short8 af[4];
#pragma unroll
    for (int mi = 0; mi < 4; ++mi) {
      int R = wr * 64 + mi * 16 + lr;
      int p0 = (2 * kg) ^ (R & 7);
      int p1 = (2 * kg + 1) ^ (R & 7);
      fvec4 f0 = *(const fvec4*)&A[buf][R * 32 + p0 * 4];
      fvec4 f1 = *(const fvec4*)&A[buf][R * 32 + p1 * 4];
      ushortx8 pk;
      pk[0] = f2bf_hw(f0.x); pk[1] = f2bf_hw(f0.y); pk[2] = f2bf_hw(f0.z); pk[3] = f2bf_hw(f0.w);
      pk[4] = f2bf_hw(f1.x); pk[5] = f2bf_hw(f1.y); pk[6] = f2bf_hw(f1.z); pk[7] = f2bf_hw(f1.w);
      af[mi] = __builtin_bit_cast(short8, pk);
    }
    __builtin_amdgcn_s_setprio(1);
#pragma unroll
    for (int ni = 0; ni < 4; ++ni)
#pragma unroll
      for (int mi = 0; mi < 4; ++mi)
        acc[mi][ni] = __builtin_amdgcn_mfma_f32_16x16x32_bf16(af[mi], ring[ni], acc[mi][ni], 0, 0, 0);
    __builtin_amdgcn_s_setprio(0);
    if (c + 2 < 32) loadB1(c + 2, ring);
    __syncthreads();
  };

  stageA(0, 0);
  short8 rgA[4], rgB[4];
  loadB1(0, rgA); loadB1(1, rgB);
  __syncthreads();
  for (int c = 0; c < 32; c += 2) {
    step(c, 0, rgA);
    step(c + 1, 1, rgB);
  }

  // epilogue: bias + celu -> h1g (bucket-ordered, guarded)
#pragma unroll
  for (int ni = 0; ni < 4; ++ni) {
    int col = wc * 64 + ni * 16 + lr;
    float bias = b1[e * N1 + col];
#pragma unroll
    for (int mi = 0; mi < 4; ++mi)
#pragma unroll
      for (int rr = 0; rr < 4; ++rr) {
        int row = wr * 64 + mi * 16 + kg * 4 + rr;
        if (row < mcount)
          h1g[(size_t)(base + row) * N1 + col] = f2bf_hw(celu_f(acc[mi][ni][rr] + bias));
      }
  }
}

// ---------------- K2: layers 2/3 + head, 64 atoms/block, 4 waves ----------------
__global__ __launch_bounds__(256, 2) void mlp23(
    const int* __restrict__ idx, const int* __restrict__ counts,
    const int* __restrict__ offsets, const int* __restrict__ gstart,
    const u16* __restrict__ h1g,
    const u16* __restrict__ W2t, const float* __restrict__ b2,
    const u16* __restrict__ W3t, const float* __restrict__ b3,
    const u16* __restrict__ Wht, const float* __restrict__ bh,
    float* __restrict__ out) {
  // [0, 32768): A tile (64 rows x 512B, source-swizzled); later H3 (64*H3P u16)
  // [32768, ...): H2 (64*H2P u16)
  __shared__ __align__(16) unsigned char SM[32768 + 64 * H2P * 2];
  u16* H2 = (u16*)(SM + 32768);
  u16* H3 = (u16*)SM;

  int bid = blockIdx.x;
  if (bid >= gstart[NS]) return;
  int e = 0;
#pragma unroll
  for (int s = 1; s < NS; ++s)
    if (bid >= gstart[s]) e = s;
  int t0 = bid - gstart[e];
  int base = offsets[e] + (t0 << 6);
  int mcount = counts[e] - (t0 << 6);
  if (mcount > 64) mcount = 64;

  int tid = threadIdx.x, lane = tid & 63, w = tid >> 6;
  int lr = lane & 15, kg = lane >> 4;

  // ---- stage A = h1 tile (64 x 256 bf16) via gl_lds, source pre-swizzled ----
  // call j: lane writes LDS byte w*8192 + j*1024 + lane*16
  // -> row r = w*16 + 2j + (lane>>5), phys 16B-unit p = lane&31, logical g = p ^ (r&7)
  {
    const u16* h1base = h1g + (size_t)base * N1;
    int p = lane & 31;
#pragma unroll
    for (int j = 0; j < 8; ++j) {
      int rrow = w * 16 + 2 * j + (lane >> 5);
      int rc = rrow < mcount ? rrow : mcount - 1;
      int g = p ^ (rrow & 7);
      gload_lds16(h1base + (size_t)rc * N1 + g * 8, SM + w * 8192 + j * 1024);
    }
  }

  // layer-2 B ring prefetch (before the stage barrier; registers survive it)
  int mr2 = (w & 1) * 32;
  int nc2 = (w >> 1) * 96;
  const u16* Wb2 = W2t + ((size_t)e * N2 + (nc2 + lr)) * N1 + kg * 8;
  auto loadB2 = [&](int ks, short8 (&d)[6]) {
#pragma unroll
    for (int ni = 0; ni < 6; ++ni)
      d[ni] = *(const short8*)(Wb2 + (size_t)ni * 16 * N1 + ks * 32);
  };
  short8 r2a[6], r2b[6];
  loadB2(0, r2a); loadB2(1, r2b);
  __syncthreads();   // drains gl_lds; A readable by all waves

  // ---- layer 2: [64 x 256] @ [256 x 192], A from swizzled LDS, no barriers ----
  f32x4 acc2[2][6] = {};
  auto ldA = [&](int R, int ks) -> short8 {
    int u = ks * 4 + kg;
    int p = u ^ (R & 7);
    return *(const short8*)(SM + R * 512 + p * 16);
  };
  auto mm2 = [&](int ks, short8 (&b)[6]) {
    short8 a0 = ldA(mr2 + lr, ks);
    short8 a1 = ldA(mr2 + 16 + lr, ks);
#pragma unroll
    for (int ni = 0; ni < 6; ++ni) {
      acc2[0][ni] = __builtin_amdgcn_mfma_f32_16x16x32_bf16(a0, b[ni], acc2[0][ni], 0, 0, 0);
      acc2[1][ni] = __builtin_amdgcn_mfma_f32_16x16x32_bf16(a1, b[ni], acc2[1][ni], 0, 0, 0);
    }
  };
  mm2(0, r2a); loadB2(2, r2a);
  mm2(1, r2b); loadB2(3, r2b);
  mm2(2, r2a); loadB2(4, r2a);
  mm2(3, r2b); loadB2(5, r2b);
  mm2(4, r2a); loadB2(6, r2a);
  mm2(5, r2b); loadB2(7, r2b);
  mm2(6, r2a);
  mm2(7, r2b);

  // layer-3 B ring prefetch (hoisted above epilogue-2 barrier)
  int mr3 = (w & 1) * 32;
  int nc3 = (w >> 1) * 80;
  const u16* Wb3 = W3t + ((size_t)e * N3 + (nc3 + lr)) * N2 + kg * 8;
  auto loadB3 = [&](int ks, short8 (&d)[5]) {
#pragma unroll
    for (int ni = 0; ni < 5; ++ni)
      d[ni] = *(const short8*)(Wb3 + (size_t)ni * 16 * N2 + ks * 32);
  };
  short8 r3a[5], r3b[5];
  loadB3(0, r3a); loadB3(1, r3b);

  // epilogue 2 -> H2
#pragma unroll
  for (int ni = 0; ni < 6; ++ni) {
    int col = nc2 + ni * 16 + lr;
    float bias = b2[e * N2 + col];
#pragma unroll
    for (int mi = 0; mi < 2; ++mi)
#pragma unroll
      for (int rr = 0; rr < 4; ++rr)
        H2[(mr2 + mi * 16 + kg * 4 + rr) * H2P + col] = f2bf_hw(celu_f(acc2[mi][ni][rr] + bias));
  }
  BAR();

  // ---- layer 3: A from H2 (pitch 200 -> 2-way banks), no barriers ----
  f32x4 acc3[2][5] = {};
  auto mm3 = [&](int ks, short8 (&b)[5]) {
    short8 a0 = *(const short8*)&H2[(mr3 + lr) * H2P + ks * 32 + kg * 8];
    short8 a1 = *(const short8*)&H2[(mr3 + 16 + lr) * H2P + ks * 32 + kg * 8];
#pragma unroll
    for (int ni = 0; ni < 5; ++ni) {
      acc3[0][ni] = __builtin_amdgcn_mfma_f32_16x16x32_bf16(a0, b[ni], acc3[0][ni], 0, 0, 0);
      acc3[1][ni] = __builtin_amdgcn_mfma_f32_16x16x32_bf16(a1, b[ni], acc3[1][ni], 0, 0, 0);
    }
  };
  mm3(0, r3a); loadB3(2, r3a);
  mm3(1, r3b); loadB3(3, r3b);
  mm3(2, r3a); loadB3(4, r3a);
  mm3(3, r3b); loadB3(5, r3b);
  mm3(4, r3a);
  mm3(5, r3b);

  // head weights prefetch (hoisted above epilogue-3 barrier)
  int hr_ = tid >> 2;
  int ho = (tid >> 1) & 1;
  int kh = tid & 1;
  const u16* wrp = Wht + ((size_t)e * 2 + ho) * N3 + kh * 80;
  ushortx8 wvv[10];
#pragma unroll
  for (int c = 0; c < 10; ++c) wvv[c] = *(const ushortx8*)&wrp[c * 8];

  // epilogue 3 -> H3 (aliases A region; all A reads finished before epilogue-2 BAR)
#pragma unroll
  for (int ni = 0; ni < 5; ++ni) {
    int col = nc3 + ni * 16 + lr;
    float bias = b3[e * N3 + col];
#pragma unroll
    for (int mi = 0; mi < 2; ++mi)
#pragma unroll
      for (int rr = 0; rr < 4; ++rr)
        H3[(mr3 + mi * 16 + kg * 4 + rr) * H3P + col] = f2bf_hw(celu_f(acc3[mi][ni][rr] + bias));
  }
  BAR();

  // head
  {
    float s = 0.f;
    const u16* hrow = &H3[hr_ * H3P + kh * 80];
#pragma unroll
    for (int c = 0; c < 10; ++c) {
      ushortx8 hv = *(const ushortx8*)&hrow[c * 8];
#pragma unroll
      for (int j = 0; j < 8; ++j) s += bf2f(hv[j]) * bf2f(wvv[c][j]);
    }
    s += __shfl_xor(s, 1);
    if (kh == 0 && hr_ < mcount) out[(size_t)idx[base + hr_] * 2 + ho] = s + bh[e * 2 + ho];
  }
}

extern "C" void kernel_launch(void* const* d_in, const int* in_sizes, int n_in,
                              void* d_out, int out_size, void* d_ws, size_t ws_size,
                              hipStream_t stream) {
  const int* species = (const int*)d_in[0];
  const float* aev = (const float*)d_in[1];
  const float* W1 = (const float*)d_in[2];
  const float* b1 = (const float*)d_in[3];
  const float* W2 = (const float*)d_in[4];
  const float* b2 = (const float*)d_in[5];
  const float* W3 = (const float*)d_in[6];
  const float* b3 = (const float*)d_in[7];
  const float* Wh = (const float*)d_in[8];
  const float* bh = (const float*)d_in[9];
  float* out = (float*)d_out;

  char* p = (char*)d_ws;
  u16* h1g = (u16*)p; p += (size_t)(NA + 256) * N1 * 2;   // 67.2 MB
  int* counts = (int*)p; p += 32;
  int* offsets = (int*)p; p += 64;
  int* cursors = (int*)p; p += 32;
  int* gstart1 = (int*)p; p += 64;
  int* gstart2 = (int*)p; p += 64;
  int* idx = (int*)p; p += (size_t)NA * 4;
  u16* W1t = (u16*)p; p += (size_t)NS * N1 * KP1 * 2;
  u16* W2t = (u16*)p; p += (size_t)NS * N2 * N1 * 2;
  u16* W3t = (u16*)p; p += (size_t)NS * N3 * N2 * 2;
  u16* Wht = (u16*)p; p += (size_t)NS * 2 * N3 * 2;

  (void)hipMemsetAsync(counts, 0, 32, stream);
  count_kernel<<<NA / 256, 256, 0, stream>>>(species, counts);
  scan_kernel<<<1, 1, 0, stream>>>(counts, offsets, cursors, gstart1, gstart2);
  scatter_kernel<<<NA / 256, 256, 0, stream>>>(species, cursors, idx);

  convert_w<<<2048, 256, 0, stream>>>(W1, W1t, AEVD, N1, KP1);
  convert_w<<<1024, 256, 0, stream>>>(W2, W2t, N1, N2, N1);
  convert_w<<<512, 256, 0, stream>>>(W3, W3t, N2, N3, N2);
  convert_w<<<16, 256, 0, stream>>>(Wh, Wht, N3, 2, N3);

  int grid1 = (NA >> 7) + NS;
  gemm1<<<grid1, 512, 0, stream>>>(idx, counts, offsets, gstart1, aev, W1t, b1, h1g);

  int grid2 = (NA >> 6) + NS;
  mlp23<<<grid2, 256, 0, stream>>>(idx, counts, offsets, gstart2, h1g,
                                   W2t, b2, W3t, b3, Wht, bh, out);
}